// Round 11
// baseline (148.534 us; speedup 1.0000x reference)
//
#include <hip/hip_runtime.h>
#include <hip/hip_bf16.h>

#define B_NUM 4
#define S_DIM 2048
#define D_DIM 1024
#define O_DIM 1024
#define E_NUM 16
#define K_SEL 512

typedef __attribute__((ext_vector_type(4))) float f32x4;
typedef __attribute__((ext_vector_type(8))) short s16x8;
typedef __attribute__((ext_vector_type(8))) unsigned short u16x8;

__device__ __forceinline__ unsigned short f2b(float f) {
  __hip_bfloat16 h = __float2bfloat16(f);   // HW cvt (RNE); pairs fuse to v_cvt_pk_bf16_f32
  unsigned short u;
  __builtin_memcpy(&u, &h, 2);
  return u;
}
__device__ __forceinline__ float b2f(unsigned short h) {
  union { unsigned int u; float f; } c; c.u = (unsigned int)h << 16; return c.f;
}

// ---------------- gw[d][e] -> gwT[e][d] + zero cnt ----------------
__global__ __launch_bounds__(256) void gwt_kernel(const float* __restrict__ gw,
                                                  float* __restrict__ gwt,
                                                  int* __restrict__ cnt) {
  if (blockIdx.x < 64) {
    int i = blockIdx.x * 256 + threadIdx.x;   // 16384 elements
    int e = i >> 10, d = i & 1023;
    gwt[i] = gw[d * E_NUM + e];
  } else {
    int i = (blockIdx.x - 64) * 256 + threadIdx.x;  // 2048 threads x int4 = 8192 ints
    reinterpret_cast<int4*>(cnt)[i] = make_int4(0, 0, 0, 0);
  }
}

// ---------------- fused prep: blocks [0,4096) transpose w; [4096,6144) gate+convert ----------------
__global__ __launch_bounds__(256) void prep_kernel(const float* __restrict__ w,
                                                   unsigned short* __restrict__ wt,
                                                   const float* __restrict__ x,
                                                   const float* __restrict__ gwt,
                                                   const float* __restrict__ gb,
                                                   float* __restrict__ logits_t,
                                                   unsigned short* __restrict__ xb) {
  if (blockIdx.x < 4096) {
    __shared__ float tile[64][65];
    int bx = blockIdx.x;
    int e = bx >> 8, d0 = ((bx >> 4) & 15) * 64, o0 = (bx & 15) * 64;
    int tx = threadIdx.x & 15, ty = threadIdx.x >> 4;
    const float* wbase = w + (size_t)e * D_DIM * O_DIM;
#pragma unroll
    for (int r = 0; r < 4; ++r) {
      int row = r * 16 + ty;
      float4 v = *reinterpret_cast<const float4*>(&wbase[(size_t)(d0 + row) * O_DIM + o0 + tx * 4]);
      tile[row][tx * 4 + 0] = v.x; tile[row][tx * 4 + 1] = v.y;
      tile[row][tx * 4 + 2] = v.z; tile[row][tx * 4 + 3] = v.w;
    }
    __syncthreads();
    unsigned short* wtb = wt + (size_t)e * O_DIM * D_DIM;
    int cg = threadIdx.x & 7;      // d-group of 8
    int oy = threadIdx.x >> 3;     // 0..31
#pragma unroll
    for (int r = 0; r < 2; ++r) {
      int orow = r * 32 + oy;
      u16x8 u;
#pragma unroll
      for (int j = 0; j < 8; ++j) u[j] = f2b(tile[cg * 8 + j][orow]);
      *reinterpret_cast<u16x8*>(&wtb[(size_t)(o0 + orow) * D_DIM + d0 + cg * 8]) = u;
    }
  } else {
    int wave = ((blockIdx.x - 4096) * 256 + threadIdx.x) >> 6;  // token index
    int ln = threadIdx.x & 63;
    int bi = wave / S_DIM, s = wave % S_DIM;
    const float* xr = x + (size_t)wave * D_DIM;
    unsigned short* xbr = xb + (size_t)wave * D_DIM;
    float acc[E_NUM];
#pragma unroll
    for (int e = 0; e < E_NUM; ++e) acc[e] = 0.f;
#pragma unroll
    for (int it = 0; it < 4; ++it) {
      int d0 = it * 256 + ln * 4;
      float4 xv = *reinterpret_cast<const float4*>(&xr[d0]);
      ushort4 u;
      u.x = f2b(xv.x); u.y = f2b(xv.y); u.z = f2b(xv.z); u.w = f2b(xv.w);
      *reinterpret_cast<ushort4*>(&xbr[d0]) = u;
#pragma unroll
      for (int e = 0; e < E_NUM; ++e) {
        float4 gv = *reinterpret_cast<const float4*>(&gwt[e * D_DIM + d0]);
        acc[e] = fmaf(xv.x, gv.x, fmaf(xv.y, gv.y,
                 fmaf(xv.z, gv.z, fmaf(xv.w, gv.w, acc[e]))));
      }
    }
    float myv = 0.f;
#pragma unroll
    for (int e = 0; e < E_NUM; ++e) {
      float v = acc[e];
#pragma unroll
      for (int o = 32; o > 0; o >>= 1) v += __shfl_xor(v, o);
      if (ln == e) myv = v;
    }
    if (ln < E_NUM)
      logits_t[((size_t)bi * E_NUM + ln) * S_DIM + s] = myv + gb[ln];
  }
}

// ---------------- per-(b,e): softmax consts + radix-select top-512 + inverted index ----------------
// 1024 threads, 2 elems/thread; wave-parallel reductions and suffix-scans (no serial tid0 loops).
__global__ __launch_bounds__(1024) void topk_kernel(const float* __restrict__ logits_t,
                                                    float* __restrict__ vals, int* __restrict__ idxb,
                                                    int* __restrict__ cnt, int* __restrict__ hslot) {
  __shared__ float fred[16];
  __shared__ int hist[256];
  __shared__ int sc[257];          // sc[256] = 0 sentinel
  __shared__ int wtot[4];
  __shared__ unsigned sh_prefix;
  __shared__ int sh_need;
  __shared__ int outc;
  __shared__ unsigned tiebm[64];
  __shared__ int wordpfx[64];

  const int row = blockIdx.x;           // b*E + e
  const int bi = row >> 4, ei = row & 15;
  const int tid = threadIdx.x;
  const int ln = tid & 63, wid = tid >> 6;
  const float* lp = logits_t + (size_t)row * S_DIM;

  const float v0 = lp[tid], v1 = lp[1024 + tid];
  const unsigned u0 = __float_as_uint(v0), u1 = __float_as_uint(v1);
  const unsigned k0 = (u0 & 0x80000000u) ? ~u0 : (u0 | 0x80000000u);
  const unsigned k1 = (u1 & 0x80000000u) ? ~u1 : (u1 | 0x80000000u);

  // block max
  float m = fmaxf(v0, v1);
#pragma unroll
  for (int o = 32; o > 0; o >>= 1) m = fmaxf(m, __shfl_xor(m, o));
  if (ln == 0) fred[wid] = m;
  __syncthreads();
  float mx = fred[0];
#pragma unroll
  for (int w2 = 1; w2 < 16; ++w2) mx = fmaxf(mx, fred[w2]);
  __syncthreads();
  // block sum
  float ls = expf(v0 - mx) + expf(v1 - mx);
#pragma unroll
  for (int o = 32; o > 0; o >>= 1) ls += __shfl_xor(ls, o);
  if (ln == 0) fred[wid] = ls;
  __syncthreads();
  float Z = 0.f;
#pragma unroll
  for (int w2 = 0; w2 < 16; ++w2) Z += fred[w2];

  // radix select, MSB-first 4x8 bits
  unsigned prefix = 0;
  int need = K_SEL;
#pragma unroll
  for (int pass = 0; pass < 4; ++pass) {
    const int shift = 24 - pass * 8;
    const unsigned pmask = (pass == 0) ? 0u : (0xFFFFFFFFu << (shift + 8));
    __syncthreads();
    if (tid < 256) hist[tid] = 0;
    __syncthreads();
    if ((k0 & pmask) == prefix) atomicAdd(&hist[(k0 >> shift) & 0xFF], 1);
    if ((k1 & pmask) == prefix) atomicAdd(&hist[(k1 >> shift) & 0xFF], 1);
    __syncthreads();
    if (tid < 256) {
      int s = hist[tid];
#pragma unroll
      for (int o = 1; o < 64; o <<= 1) {     // wave suffix-scan
        int t = __shfl_down(s, o);
        if (ln + o < 64) s += t;
      }
      if (ln == 0) wtot[tid >> 6] = s;
      sc[tid] = s;
    }
    if (tid == 0) sc[256] = 0;
    __syncthreads();
    if (tid < 256) {
      int add = 0;
#pragma unroll
      for (int w2 = 1; w2 < 4; ++w2) if (w2 > (tid >> 6)) add += wtot[w2];
      sc[tid] += add;
    }
    __syncthreads();
    if (tid < 256) {
      bool c  = sc[tid] >= need;
      bool cn = sc[tid + 1] >= need;
      if (c && !cn) {
        sh_prefix = prefix | ((unsigned)tid << shift);
        sh_need = need - sc[tid + 1];
      }
    }
    __syncthreads();
    prefix = sh_prefix;
    need = sh_need;
  }
  const unsigned T = prefix;
  const int need_rem = need;

  if (tid == 0) outc = 0;
  if (tid < 64) tiebm[tid] = 0;
  __syncthreads();

  if (k0 > T) {
    int p = atomicAdd(&outc, 1);
    vals[row * K_SEL + p] = expf(v0 - mx) / Z;
    idxb[row * K_SEL + p] = tid;
    int hp = atomicAdd(&cnt[bi * S_DIM + tid], 1);
    hslot[(bi * S_DIM + tid) * 16 + hp] = ei * K_SEL + p;
  } else if (k0 == T) {
    atomicOr(&tiebm[tid >> 5], 1u << (tid & 31));
  }
  if (k1 > T) {
    const int s = 1024 + tid;
    int p = atomicAdd(&outc, 1);
    vals[row * K_SEL + p] = expf(v1 - mx) / Z;
    idxb[row * K_SEL + p] = s;
    int hp = atomicAdd(&cnt[bi * S_DIM + s], 1);
    hslot[(bi * S_DIM + s) * 16 + hp] = ei * K_SEL + p;
  } else if (k1 == T) {
    atomicOr(&tiebm[(1024 + tid) >> 5], 1u << (tid & 31));
  }
  __syncthreads();
  if (tid == 0) {
    int c = 0;
    for (int w2 = 0; w2 < 64; ++w2) { wordpfx[w2] = c; c += __popc(tiebm[w2]); }
  }
  __syncthreads();
  if (tid < 64) {
    unsigned mbits = tiebm[tid];
    int base = wordpfx[tid];
    const int p0 = outc;
    while (mbits) {
      int bit = __ffs(mbits) - 1;
      mbits &= mbits - 1;
      if (base < need_rem) {
        int s = tid * 32 + bit;
        int p = p0 + base;
        vals[row * K_SEL + p] = expf(lp[s] - mx) / Z;
        idxb[row * K_SEL + p] = s;
        int hp = atomicAdd(&cnt[bi * S_DIM + s], 1);
        hslot[(bi * S_DIM + s) * 16 + hp] = ei * K_SEL + p;
      }
      base++;
    }
  }
}

// ---------------- grouped GEMM: 256x256, BK=64, 8 waves, phased schedule, counted vmcnt ----------------
// (R5-proven K-loop schedule, frozen.) NEW: epilogue repacks C through LDS (per-wave 16KB region,
// XOR granule swizzle) so global stores are 16B coalesced (8 lanes cover a 128B row segment).
__global__ __launch_bounds__(512, 1) void moe_gemm_kernel(
    const unsigned short* __restrict__ xb,   // [B,S,D] bf16
    const unsigned short* __restrict__ wt,   // [E,O,D] bf16
    const int* __restrict__ idxbuf,          // [B*E,K]
    const float* __restrict__ valbuf,        // [B*E,K]
    const float* __restrict__ bias,          // [E]
    unsigned short* __restrict__ tmp)        // [B*E,K,O] bf16
{
  __shared__ __align__(16) unsigned short lA[2][256 * 64];
  __shared__ __align__(16) unsigned short lB[2][256 * 64];

  const int tid = threadIdx.x;
  const int wv = tid >> 6, ln = tid & 63;
  const int wm = wv >> 2, wn = wv & 3;

  const int bid = blockIdx.x;
  const int swz = (bid & 7) * 64 + (bid >> 3);   // XCD-chunked (512 % 8 == 0, bijective)
  const int n0 = (swz & 3) * 256;
  const int m0 = ((swz >> 2) & 1) * 256;
  const int grp = swz >> 3;                // b*E + e
  const int bi = grp >> 4, ei = grp & 15;

  const unsigned short* aSrcP[4];
  const unsigned short* bSrcP[4];
  const int lslot = (ln & 7) ^ (ln >> 3);
#pragma unroll
  for (int s = 0; s < 4; ++s) {
    const int r = s * 64 + wv * 8 + (ln >> 3);
    const int tok = idxbuf[grp * K_SEL + m0 + r];
    aSrcP[s] = xb + ((size_t)bi * S_DIM + tok) * D_DIM + lslot * 8;
    bSrcP[s] = wt + ((size_t)ei * O_DIM + (n0 + r)) * D_DIM + lslot * 8;
  }

  const unsigned rowA = wm * 128 + (ln & 15);
  const unsigned rowB = wn * 64 + (ln & 15);
  const unsigned phys0 = (ln >> 4) ^ (ln & 7);
  const unsigned phys1 = (4 + (ln >> 4)) ^ (ln & 7);

  f32x4 acc[8][4];
  f32x4 zero4 = {0.f, 0.f, 0.f, 0.f};
#pragma unroll
  for (int i = 0; i < 8; ++i)
#pragma unroll
    for (int j = 0; j < 4; ++j) acc[i][j] = zero4;

  s16x8 bfr[4][2];

#define GLD(dst, src)                                                          \
  __builtin_amdgcn_global_load_lds(                                            \
      (const __attribute__((address_space(1))) void*)(src),                    \
      (__attribute__((address_space(3))) void*)(dst), 16, 0, 0)
#define VMW(N) asm volatile("s_waitcnt vmcnt(" #N ")" ::: "memory")
#define LGKM0 asm volatile("s_waitcnt lgkmcnt(0)" ::: "memory")
#define DS_A(CUR, i, PH) (*(const s16x8*)&lA[CUR][rowA * 64u + (i) * 1024u + (PH) * 8u])
#define DS_B(CUR, j, PH) (*(const s16x8*)&lB[CUR][rowB * 64u + (j) * 1024u + (PH) * 8u])

#define MFMA16(P)                                                              \
  __builtin_amdgcn_s_setprio(1);                                               \
  _Pragma("unroll") for (int jj = 0; jj < 4; ++jj) {                           \
    acc[2*(P)][jj]   = __builtin_amdgcn_mfma_f32_16x16x32_bf16(aL0, bfr[jj][0], acc[2*(P)][jj], 0, 0, 0);   \
    acc[2*(P)][jj]   = __builtin_amdgcn_mfma_f32_16x16x32_bf16(aL1, bfr[jj][1], acc[2*(P)][jj], 0, 0, 0);   \
    acc[2*(P)+1][jj] = __builtin_amdgcn_mfma_f32_16x16x32_bf16(aH0, bfr[jj][0], acc[2*(P)+1][jj], 0, 0, 0); \
    acc[2*(P)+1][jj] = __builtin_amdgcn_mfma_f32_16x16x32_bf16(aH1, bfr[jj][1], acc[2*(P)+1][jj], 0, 0, 0); \
  }                                                                            \
  __builtin_amdgcn_s_setprio(0);

#define KTILE(CUR, NXT, KT, DOSTAGE, VM1, VM3)                                 \
  {                                                                            \
    { /* phase 0 */                                                            \
      _Pragma("unroll") for (int jj = 0; jj < 4; ++jj) {                       \
        bfr[jj][0] = DS_B(CUR, jj, phys0);                                     \
        bfr[jj][1] = DS_B(CUR, jj, phys1);                                     \
      }                                                                        \
      s16x8 aL0 = DS_A(CUR, 0, phys0), aL1 = DS_A(CUR, 0, phys1);              \
      s16x8 aH0 = DS_A(CUR, 1, phys0), aH1 = DS_A(CUR, 1, phys1);              \
      if (DOSTAGE) {                                                           \
        GLD(&lB[NXT][(wv * 8) * 64],        bSrcP[0] + (KT) * 64);             \
        GLD(&lB[NXT][(64 + wv * 8) * 64],   bSrcP[1] + (KT) * 64);             \
      }                                                                        \
      __builtin_amdgcn_s_barrier();                                            \
      LGKM0; __builtin_amdgcn_sched_barrier(0);                                \
      MFMA16(0);                                                               \
      __builtin_amdgcn_s_barrier();                                            \
    }                                                                          \
    { /* phase 1 */                                                            \
      s16x8 aL0 = DS_A(CUR, 2, phys0), aL1 = DS_A(CUR, 2, phys1);              \
      s16x8 aH0 = DS_A(CUR, 3, phys0), aH1 = DS_A(CUR, 3, phys1);              \
      if (DOSTAGE) {                                                           \
        GLD(&lB[NXT][(128 + wv * 8) * 64],  bSrcP[2] + (KT) * 64);             \
        GLD(&lB[NXT][(192 + wv * 8) * 64],  bSrcP[3] + (KT) * 64);             \
      }                                                                        \
      VM1;                                                                     \
      __builtin_amdgcn_s_barrier();                                            \
      LGKM0; __builtin_amdgcn_sched_barrier(0);                                \
      MFMA16(1);                                                               \
      __builtin_amdgcn_s_barrier();                                            \
    }                                                                          \
    { /* phase 2 */                                                            \
      s16x8 aL0 = DS_A(CUR, 4, phys0), aL1 = DS_A(CUR, 4, phys1);              \
      s16x8 aH0 = DS_A(CUR, 5, phys0), aH1 = DS_A(CUR, 5, phys1);              \
      if (DOSTAGE) {                                                           \
        GLD(&lA[NXT][(wv * 8) * 64],        aSrcP[0] + (KT) * 64);             \
        GLD(&lA[NXT][(128 + wv * 8) * 64],  aSrcP[2] + (KT) * 64);             \
      }                                                                        \
      __builtin_amdgcn_s_barrier();                                            \
      LGKM0; __builtin_amdgcn_sched_barrier(0);                                \
      MFMA16(2);                                                               \
      __builtin_amdgcn_s_barrier();                                            \
    }                                                                          \
    { /* phase 3 */                                                            \
      s16x8 aL0 = DS_A(CUR, 6, phys0), aL1 = DS_A(CUR, 6, phys1);              \
      s16x8 aH0 = DS_A(CUR, 7, phys0), aH1 = DS_A(CUR, 7, phys1);              \
      if (DOSTAGE) {                                                           \
        GLD(&lA[NXT][(64 + wv * 8) * 64],   aSrcP[1] + (KT) * 64);             \
        GLD(&lA[NXT][(192 + wv * 8) * 64],  aSrcP[3] + (KT) * 64);             \
      }                                                                        \
      VM3;                                                                     \
      __builtin_amdgcn_s_barrier();                                            \
      LGKM0; __builtin_amdgcn_sched_barrier(0);                                \
      MFMA16(3);                                                               \
      __builtin_amdgcn_s_barrier();                                            \
    }                                                                          \
  }

  GLD(&lB[0][(wv * 8) * 64],        bSrcP[0]);
  GLD(&lB[0][(64 + wv * 8) * 64],   bSrcP[1]);
  GLD(&lB[0][(128 + wv * 8) * 64],  bSrcP[2]);
  GLD(&lB[0][(192 + wv * 8) * 64],  bSrcP[3]);
  GLD(&lA[0][(wv * 8) * 64],        aSrcP[0]);
  GLD(&lA[0][(128 + wv * 8) * 64],  aSrcP[2]);
  GLD(&lA[0][(64 + wv * 8) * 64],   aSrcP[1]);
  GLD(&lA[0][(192 + wv * 8) * 64],  aSrcP[3]);
  VMW(0);
  __builtin_amdgcn_s_barrier();

  for (int t = 0; t < 14; t += 2) {
    KTILE(0, 1, t + 1, 1, VMW(4), VMW(2));
    KTILE(1, 0, t + 2, 1, VMW(4), VMW(2));
  }
  KTILE(0, 1, 15, 1, VMW(4), VMW(2));
  KTILE(1, 0, 0, 0, VMW(0), ((void)0));

  // ---- epilogue: (acc + b)/val -> bf16, repack via LDS, 16B coalesced stores ----
  const float be = bias[ei];
  unsigned short* wls = (wv < 4) ? ((unsigned short*)lA + wv * 8192)
                                 : ((unsigned short*)lB + (wv - 4) * 8192);
  const int rgrp = ln >> 4;        // 0..3
  const int c0 = ln & 15;
#pragma unroll
  for (int i = 0; i < 8; ++i) {
#pragma unroll
    for (int r = 0; r < 4; ++r) {
      const int row_l = i * 16 + rgrp * 4 + r;
      const int krow = m0 + wm * 128 + row_l;
      const float inv = 1.0f / valbuf[grp * K_SEL + krow];
#pragma unroll
      for (int j = 0; j < 4; ++j) {
        const int col = j * 16 + c0;
        const int gph = (col >> 3) ^ (row_l & 7);       // granule swizzle
        wls[row_l * 64 + gph * 8 + (col & 7)] = f2b((acc[i][j][r] + be) * inv);
      }
    }
  }
  __syncthreads();
#pragma unroll
  for (int it = 0; it < 16; ++it) {
    const int row_l = it * 8 + (ln >> 3);
    const int g = ln & 7;
    const int gph = g ^ (row_l & 7);
    u16x8 v = *(const u16x8*)&wls[row_l * 64 + gph * 8];
    unsigned short* dst = tmp + ((size_t)grp * K_SEL + m0 + wm * 128 + row_l) * O_DIM
                        + n0 + wn * 64 + g * 8;
    *(u16x8*)dst = v;
  }
#undef GLD
#undef VMW
#undef LGKM0
#undef DS_A
#undef DS_B
#undef MFMA16
#undef KTILE
}

// ---------------- per-token gather-reduce: 2 tokens/block, 16B loads ----------------
__global__ __launch_bounds__(256) void reduce_kernel(const unsigned short* __restrict__ tmp,
                                                     const int* __restrict__ cnt,
                                                     const int* __restrict__ hslot,
                                                     float* __restrict__ out) {
  const int t = blockIdx.x * 2 + (threadIdx.x >> 7);   // b*S + s
  const int bi = t >> 11;
  const int l = threadIdx.x & 127;
  const int n = cnt[t];
  float a[8] = {0.f, 0.f, 0.f, 0.f, 0.f, 0.f, 0.f, 0.f};
  for (int h = 0; h < n; ++h) {
    const int u = hslot[t * 16 + h];  // e*K + p
    const u16x8 q = *reinterpret_cast<const u16x8*>(
        tmp + ((size_t)bi * E_NUM * K_SEL + u) * O_DIM + l * 8);
#pragma unroll
    for (int j = 0; j < 8; ++j) a[j] += b2f(q[j]);
  }
  float4 s0 = {a[0], a[1], a[2], a[3]};
  float4 s1 = {a[4], a[5], a[6], a[7]};
  float* op = &out[(size_t)t * O_DIM + l * 8];
  *reinterpret_cast<float4*>(op) = s0;
  *reinterpret_cast<float4*>(op + 4) = s1;
}

extern "C" void kernel_launch(void* const* d_in, const int* in_sizes, int n_in,
                              void* d_out, int out_size, void* d_ws, size_t ws_size,
                              hipStream_t stream) {
  const float* x   = (const float*)d_in[0];
  const float* gw  = (const float*)d_in[1];
  const float* gb  = (const float*)d_in[2];
  const float* w   = (const float*)d_in[3];
  const float* bia = (const float*)d_in[4];
  float* out = (float*)d_out;

  char* ws = (char*)d_ws;
  float*          logits_t = (float*)(ws + 0x0);        // 512 KB
  float*          vals     = (float*)(ws + 0x80000);    // 128 KB
  int*            idxb     = (int*)(ws + 0xA0000);      // 128 KB
  int*            cnt      = (int*)(ws + 0xC0000);      // 32 KB
  int*            hslot    = (int*)(ws + 0xC8000);      // 512 KB
  unsigned short* xbf      = (unsigned short*)(ws + 0x148000);    // 16 MB
  unsigned short* wtb      = (unsigned short*)(ws + 0x1148000);   // 32 MB
  unsigned short* tmp      = (unsigned short*)(ws + 0x3148000);   // 64 MB
  float*          gwt      = (float*)(ws + 0x7148000);            // 64 KB

  gwt_kernel<<<dim3(64 + 8), dim3(256), 0, stream>>>(gw, gwt, cnt);
  prep_kernel<<<dim3(4096 + 2048), dim3(256), 0, stream>>>(w, wtb, x, gwt, gb, logits_t, xbf);
  topk_kernel<<<dim3(B_NUM * E_NUM), dim3(1024), 0, stream>>>(logits_t, vals, idxb, cnt, hslot);
  moe_gemm_kernel<<<dim3(512), dim3(512), 0, stream>>>(xbf, wtb, idxb, vals, bia, tmp);
  reduce_kernel<<<dim3(B_NUM * S_DIM / 2), dim3(256), 0, stream>>>(tmp, cnt, hslot, out);
}

// Round 12
// 143.744 us; speedup vs baseline: 1.0333x; 1.0333x over previous
//
#include <hip/hip_runtime.h>
#include <hip/hip_bf16.h>

#define B_NUM 4
#define S_DIM 2048
#define D_DIM 1024
#define O_DIM 1024
#define E_NUM 16
#define K_SEL 512

typedef __attribute__((ext_vector_type(4))) float f32x4;
typedef __attribute__((ext_vector_type(8))) short s16x8;
typedef __attribute__((ext_vector_type(8))) unsigned short u16x8;

__device__ __forceinline__ unsigned short f2b(float f) {
  __hip_bfloat16 h = __float2bfloat16(f);   // HW cvt (RNE); pairs fuse to v_cvt_pk_bf16_f32
  unsigned short u;
  __builtin_memcpy(&u, &h, 2);
  return u;
}
__device__ __forceinline__ float b2f(unsigned short h) {
  union { unsigned int u; float f; } c; c.u = (unsigned int)h << 16; return c.f;
}

// ---------------- gw[d][e] -> gwT[e][d] + zero cnt ----------------
__global__ __launch_bounds__(256) void gwt_kernel(const float* __restrict__ gw,
                                                  float* __restrict__ gwt,
                                                  int* __restrict__ cnt) {
  if (blockIdx.x < 64) {
    int i = blockIdx.x * 256 + threadIdx.x;   // 16384 elements
    int e = i >> 10, d = i & 1023;
    gwt[i] = gw[d * E_NUM + e];
  } else {
    int i = (blockIdx.x - 64) * 256 + threadIdx.x;  // 2048 threads x int4 = 8192 ints
    reinterpret_cast<int4*>(cnt)[i] = make_int4(0, 0, 0, 0);
  }
}

// ---------------- fused prep: blocks [0,4096) transpose w; [4096,6144) gate+convert ----------------
__global__ __launch_bounds__(256) void prep_kernel(const float* __restrict__ w,
                                                   unsigned short* __restrict__ wt,
                                                   const float* __restrict__ x,
                                                   const float* __restrict__ gwt,
                                                   const float* __restrict__ gb,
                                                   float* __restrict__ logits_t,
                                                   unsigned short* __restrict__ xb) {
  if (blockIdx.x < 4096) {
    __shared__ float tile[64][65];
    int bx = blockIdx.x;
    int e = bx >> 8, d0 = ((bx >> 4) & 15) * 64, o0 = (bx & 15) * 64;
    int tx = threadIdx.x & 15, ty = threadIdx.x >> 4;
    const float* wbase = w + (size_t)e * D_DIM * O_DIM;
#pragma unroll
    for (int r = 0; r < 4; ++r) {
      int row = r * 16 + ty;
      float4 v = *reinterpret_cast<const float4*>(&wbase[(size_t)(d0 + row) * O_DIM + o0 + tx * 4]);
      tile[row][tx * 4 + 0] = v.x; tile[row][tx * 4 + 1] = v.y;
      tile[row][tx * 4 + 2] = v.z; tile[row][tx * 4 + 3] = v.w;
    }
    __syncthreads();
    unsigned short* wtb = wt + (size_t)e * O_DIM * D_DIM;
    int cg = threadIdx.x & 7;      // d-group of 8
    int oy = threadIdx.x >> 3;     // 0..31
#pragma unroll
    for (int r = 0; r < 2; ++r) {
      int orow = r * 32 + oy;
      u16x8 u;
#pragma unroll
      for (int j = 0; j < 8; ++j) u[j] = f2b(tile[cg * 8 + j][orow]);
      *reinterpret_cast<u16x8*>(&wtb[(size_t)(o0 + orow) * D_DIM + d0 + cg * 8]) = u;
    }
  } else {
    int wave = ((blockIdx.x - 4096) * 256 + threadIdx.x) >> 6;  // token index
    int ln = threadIdx.x & 63;
    int bi = wave / S_DIM, s = wave % S_DIM;
    const float* xr = x + (size_t)wave * D_DIM;
    unsigned short* xbr = xb + (size_t)wave * D_DIM;
    float acc[E_NUM];
#pragma unroll
    for (int e = 0; e < E_NUM; ++e) acc[e] = 0.f;
#pragma unroll
    for (int it = 0; it < 4; ++it) {
      int d0 = it * 256 + ln * 4;
      float4 xv = *reinterpret_cast<const float4*>(&xr[d0]);
      ushort4 u;
      u.x = f2b(xv.x); u.y = f2b(xv.y); u.z = f2b(xv.z); u.w = f2b(xv.w);
      *reinterpret_cast<ushort4*>(&xbr[d0]) = u;
#pragma unroll
      for (int e = 0; e < E_NUM; ++e) {
        float4 gv = *reinterpret_cast<const float4*>(&gwt[e * D_DIM + d0]);
        acc[e] = fmaf(xv.x, gv.x, fmaf(xv.y, gv.y,
                 fmaf(xv.z, gv.z, fmaf(xv.w, gv.w, acc[e]))));
      }
    }
    float myv = 0.f;
#pragma unroll
    for (int e = 0; e < E_NUM; ++e) {
      float v = acc[e];
#pragma unroll
      for (int o = 32; o > 0; o >>= 1) v += __shfl_xor(v, o);
      if (ln == e) myv = v;
    }
    if (ln < E_NUM)
      logits_t[((size_t)bi * E_NUM + ln) * S_DIM + s] = myv + gb[ln];
  }
}

// ---------------- per-(b,e): softmax consts + radix-select top-512 + inverted index ----------------
// 1024 threads, 2 elems/thread; wave-parallel reductions and suffix-scans (no serial tid0 loops).
__global__ __launch_bounds__(1024) void topk_kernel(const float* __restrict__ logits_t,
                                                    float* __restrict__ vals, int* __restrict__ idxb,
                                                    int* __restrict__ cnt, int* __restrict__ hslot) {
  __shared__ float fred[16];
  __shared__ int hist[256];
  __shared__ int sc[257];          // sc[256] = 0 sentinel
  __shared__ int wtot[4];
  __shared__ unsigned sh_prefix;
  __shared__ int sh_need;
  __shared__ int outc;
  __shared__ unsigned tiebm[64];
  __shared__ int wordpfx[64];

  const int row = blockIdx.x;           // b*E + e
  const int bi = row >> 4, ei = row & 15;
  const int tid = threadIdx.x;
  const int ln = tid & 63, wid = tid >> 6;
  const float* lp = logits_t + (size_t)row * S_DIM;

  const float v0 = lp[tid], v1 = lp[1024 + tid];
  const unsigned u0 = __float_as_uint(v0), u1 = __float_as_uint(v1);
  const unsigned k0 = (u0 & 0x80000000u) ? ~u0 : (u0 | 0x80000000u);
  const unsigned k1 = (u1 & 0x80000000u) ? ~u1 : (u1 | 0x80000000u);

  // block max
  float m = fmaxf(v0, v1);
#pragma unroll
  for (int o = 32; o > 0; o >>= 1) m = fmaxf(m, __shfl_xor(m, o));
  if (ln == 0) fred[wid] = m;
  __syncthreads();
  float mx = fred[0];
#pragma unroll
  for (int w2 = 1; w2 < 16; ++w2) mx = fmaxf(mx, fred[w2]);
  __syncthreads();
  // block sum
  float ls = expf(v0 - mx) + expf(v1 - mx);
#pragma unroll
  for (int o = 32; o > 0; o >>= 1) ls += __shfl_xor(ls, o);
  if (ln == 0) fred[wid] = ls;
  __syncthreads();
  float Z = 0.f;
#pragma unroll
  for (int w2 = 0; w2 < 16; ++w2) Z += fred[w2];

  // radix select, MSB-first 4x8 bits
  unsigned prefix = 0;
  int need = K_SEL;
#pragma unroll
  for (int pass = 0; pass < 4; ++pass) {
    const int shift = 24 - pass * 8;
    const unsigned pmask = (pass == 0) ? 0u : (0xFFFFFFFFu << (shift + 8));
    __syncthreads();
    if (tid < 256) hist[tid] = 0;
    __syncthreads();
    if ((k0 & pmask) == prefix) atomicAdd(&hist[(k0 >> shift) & 0xFF], 1);
    if ((k1 & pmask) == prefix) atomicAdd(&hist[(k1 >> shift) & 0xFF], 1);
    __syncthreads();
    if (tid < 256) {
      int s = hist[tid];
#pragma unroll
      for (int o = 1; o < 64; o <<= 1) {     // wave suffix-scan
        int t = __shfl_down(s, o);
        if (ln + o < 64) s += t;
      }
      if (ln == 0) wtot[tid >> 6] = s;
      sc[tid] = s;
    }
    if (tid == 0) sc[256] = 0;
    __syncthreads();
    if (tid < 256) {
      int add = 0;
#pragma unroll
      for (int w2 = 1; w2 < 4; ++w2) if (w2 > (tid >> 6)) add += wtot[w2];
      sc[tid] += add;
    }
    __syncthreads();
    if (tid < 256) {
      bool c  = sc[tid] >= need;
      bool cn = sc[tid + 1] >= need;
      if (c && !cn) {
        sh_prefix = prefix | ((unsigned)tid << shift);
        sh_need = need - sc[tid + 1];
      }
    }
    __syncthreads();
    prefix = sh_prefix;
    need = sh_need;
  }
  const unsigned T = prefix;
  const int need_rem = need;

  if (tid == 0) outc = 0;
  if (tid < 64) tiebm[tid] = 0;
  __syncthreads();

  if (k0 > T) {
    int p = atomicAdd(&outc, 1);
    vals[row * K_SEL + p] = expf(v0 - mx) / Z;
    idxb[row * K_SEL + p] = tid;
    int hp = atomicAdd(&cnt[bi * S_DIM + tid], 1);
    hslot[(bi * S_DIM + tid) * 16 + hp] = ei * K_SEL + p;
  } else if (k0 == T) {
    atomicOr(&tiebm[tid >> 5], 1u << (tid & 31));
  }
  if (k1 > T) {
    const int s = 1024 + tid;
    int p = atomicAdd(&outc, 1);
    vals[row * K_SEL + p] = expf(v1 - mx) / Z;
    idxb[row * K_SEL + p] = s;
    int hp = atomicAdd(&cnt[bi * S_DIM + s], 1);
    hslot[(bi * S_DIM + s) * 16 + hp] = ei * K_SEL + p;
  } else if (k1 == T) {
    atomicOr(&tiebm[(1024 + tid) >> 5], 1u << (tid & 31));
  }
  __syncthreads();
  if (tid == 0) {
    int c = 0;
    for (int w2 = 0; w2 < 64; ++w2) { wordpfx[w2] = c; c += __popc(tiebm[w2]); }
  }
  __syncthreads();
  if (tid < 64) {
    unsigned mbits = tiebm[tid];
    int base = wordpfx[tid];
    const int p0 = outc;
    while (mbits) {
      int bit = __ffs(mbits) - 1;
      mbits &= mbits - 1;
      if (base < need_rem) {
        int s = tid * 32 + bit;
        int p = p0 + base;
        vals[row * K_SEL + p] = expf(lp[s] - mx) / Z;
        idxb[row * K_SEL + p] = s;
        int hp = atomicAdd(&cnt[bi * S_DIM + s], 1);
        hslot[(bi * S_DIM + s) * 16 + hp] = ei * K_SEL + p;
      }
      base++;
    }
  }
}

// ---------------- grouped GEMM: 256x256, BK=64, 8 waves, phased schedule, counted vmcnt ----------------
// (R5-proven schedule: dbuf A + dbuf B via global_load_lds, B staged ph0-1, A staged ph2-3,
//  VMW(4)@ph1 / VMW(2)@ph3; epilogue = plain bf16 stores to dense tmp — R10-proven.)
__global__ __launch_bounds__(512, 1) void moe_gemm_kernel(
    const unsigned short* __restrict__ xb,   // [B,S,D] bf16
    const unsigned short* __restrict__ wt,   // [E,O,D] bf16
    const int* __restrict__ idxbuf,          // [B*E,K]
    const float* __restrict__ valbuf,        // [B*E,K]
    const float* __restrict__ bias,          // [E]
    unsigned short* __restrict__ tmp)        // [B*E,K,O] bf16
{
  __shared__ __align__(16) unsigned short lA[2][256 * 64];
  __shared__ __align__(16) unsigned short lB[2][256 * 64];

  const int tid = threadIdx.x;
  const int wv = tid >> 6, ln = tid & 63;
  const int wm = wv >> 2, wn = wv & 3;

  const int bid = blockIdx.x;
  const int swz = (bid & 7) * 64 + (bid >> 3);   // XCD-chunked (512 % 8 == 0, bijective)
  const int n0 = (swz & 3) * 256;
  const int m0 = ((swz >> 2) & 1) * 256;
  const int grp = swz >> 3;                // b*E + e
  const int bi = grp >> 4, ei = grp & 15;

  const unsigned short* aSrcP[4];
  const unsigned short* bSrcP[4];
  const int lslot = (ln & 7) ^ (ln >> 3);
#pragma unroll
  for (int s = 0; s < 4; ++s) {
    const int r = s * 64 + wv * 8 + (ln >> 3);
    const int tok = idxbuf[grp * K_SEL + m0 + r];
    aSrcP[s] = xb + ((size_t)bi * S_DIM + tok) * D_DIM + lslot * 8;
    bSrcP[s] = wt + ((size_t)ei * O_DIM + (n0 + r)) * D_DIM + lslot * 8;
  }

  const unsigned rowA = wm * 128 + (ln & 15);
  const unsigned rowB = wn * 64 + (ln & 15);
  const unsigned phys0 = (ln >> 4) ^ (ln & 7);
  const unsigned phys1 = (4 + (ln >> 4)) ^ (ln & 7);

  f32x4 acc[8][4];
  f32x4 zero4 = {0.f, 0.f, 0.f, 0.f};
#pragma unroll
  for (int i = 0; i < 8; ++i)
#pragma unroll
    for (int j = 0; j < 4; ++j) acc[i][j] = zero4;

  s16x8 bfr[4][2];

#define GLD(dst, src)                                                          \
  __builtin_amdgcn_global_load_lds(                                            \
      (const __attribute__((address_space(1))) void*)(src),                    \
      (__attribute__((address_space(3))) void*)(dst), 16, 0, 0)
#define VMW(N) asm volatile("s_waitcnt vmcnt(" #N ")" ::: "memory")
#define LGKM0 asm volatile("s_waitcnt lgkmcnt(0)" ::: "memory")
#define DS_A(CUR, i, PH) (*(const s16x8*)&lA[CUR][rowA * 64u + (i) * 1024u + (PH) * 8u])
#define DS_B(CUR, j, PH) (*(const s16x8*)&lB[CUR][rowB * 64u + (j) * 1024u + (PH) * 8u])

#define MFMA16(P)                                                              \
  __builtin_amdgcn_s_setprio(1);                                               \
  _Pragma("unroll") for (int jj = 0; jj < 4; ++jj) {                           \
    acc[2*(P)][jj]   = __builtin_amdgcn_mfma_f32_16x16x32_bf16(aL0, bfr[jj][0], acc[2*(P)][jj], 0, 0, 0);   \
    acc[2*(P)][jj]   = __builtin_amdgcn_mfma_f32_16x16x32_bf16(aL1, bfr[jj][1], acc[2*(P)][jj], 0, 0, 0);   \
    acc[2*(P)+1][jj] = __builtin_amdgcn_mfma_f32_16x16x32_bf16(aH0, bfr[jj][0], acc[2*(P)+1][jj], 0, 0, 0); \
    acc[2*(P)+1][jj] = __builtin_amdgcn_mfma_f32_16x16x32_bf16(aH1, bfr[jj][1], acc[2*(P)+1][jj], 0, 0, 0); \
  }                                                                            \
  __builtin_amdgcn_s_setprio(0);

#define KTILE(CUR, NXT, KT, DOSTAGE, VM1, VM3)                                 \
  {                                                                            \
    { /* phase 0 */                                                            \
      _Pragma("unroll") for (int jj = 0; jj < 4; ++jj) {                       \
        bfr[jj][0] = DS_B(CUR, jj, phys0);                                     \
        bfr[jj][1] = DS_B(CUR, jj, phys1);                                     \
      }                                                                        \
      s16x8 aL0 = DS_A(CUR, 0, phys0), aL1 = DS_A(CUR, 0, phys1);              \
      s16x8 aH0 = DS_A(CUR, 1, phys0), aH1 = DS_A(CUR, 1, phys1);              \
      if (DOSTAGE) {                                                           \
        GLD(&lB[NXT][(wv * 8) * 64],        bSrcP[0] + (KT) * 64);             \
        GLD(&lB[NXT][(64 + wv * 8) * 64],   bSrcP[1] + (KT) * 64);             \
      }                                                                        \
      __builtin_amdgcn_s_barrier();                                            \
      LGKM0; __builtin_amdgcn_sched_barrier(0);                                \
      MFMA16(0);                                                               \
      __builtin_amdgcn_s_barrier();                                            \
    }                                                                          \
    { /* phase 1 */                                                            \
      s16x8 aL0 = DS_A(CUR, 2, phys0), aL1 = DS_A(CUR, 2, phys1);              \
      s16x8 aH0 = DS_A(CUR, 3, phys0), aH1 = DS_A(CUR, 3, phys1);              \
      if (DOSTAGE) {                                                           \
        GLD(&lB[NXT][(128 + wv * 8) * 64],  bSrcP[2] + (KT) * 64);             \
        GLD(&lB[NXT][(192 + wv * 8) * 64],  bSrcP[3] + (KT) * 64);             \
      }                                                                        \
      VM1;                                                                     \
      __builtin_amdgcn_s_barrier();                                            \
      LGKM0; __builtin_amdgcn_sched_barrier(0);                                \
      MFMA16(1);                                                               \
      __builtin_amdgcn_s_barrier();                                            \
    }                                                                          \
    { /* phase 2 */                                                            \
      s16x8 aL0 = DS_A(CUR, 4, phys0), aL1 = DS_A(CUR, 4, phys1);              \
      s16x8 aH0 = DS_A(CUR, 5, phys0), aH1 = DS_A(CUR, 5, phys1);              \
      if (DOSTAGE) {                                                           \
        GLD(&lA[NXT][(wv * 8) * 64],        aSrcP[0] + (KT) * 64);             \
        GLD(&lA[NXT][(128 + wv * 8) * 64],  aSrcP[2] + (KT) * 64);             \
      }                                                                        \
      __builtin_amdgcn_s_barrier();                                            \
      LGKM0; __builtin_amdgcn_sched_barrier(0);                                \
      MFMA16(2);                                                               \
      __builtin_amdgcn_s_barrier();                                            \
    }                                                                          \
    { /* phase 3 */                                                            \
      s16x8 aL0 = DS_A(CUR, 6, phys0), aL1 = DS_A(CUR, 6, phys1);              \
      s16x8 aH0 = DS_A(CUR, 7, phys0), aH1 = DS_A(CUR, 7, phys1);              \
      if (DOSTAGE) {                                                           \
        GLD(&lA[NXT][(64 + wv * 8) * 64],   aSrcP[1] + (KT) * 64);             \
        GLD(&lA[NXT][(192 + wv * 8) * 64],  aSrcP[3] + (KT) * 64);             \
      }                                                                        \
      VM3;                                                                     \
      __builtin_amdgcn_s_barrier();                                            \
      LGKM0; __builtin_amdgcn_sched_barrier(0);                                \
      MFMA16(3);                                                               \
      __builtin_amdgcn_s_barrier();                                            \
    }                                                                          \
  }

  GLD(&lB[0][(wv * 8) * 64],        bSrcP[0]);
  GLD(&lB[0][(64 + wv * 8) * 64],   bSrcP[1]);
  GLD(&lB[0][(128 + wv * 8) * 64],  bSrcP[2]);
  GLD(&lB[0][(192 + wv * 8) * 64],  bSrcP[3]);
  GLD(&lA[0][(wv * 8) * 64],        aSrcP[0]);
  GLD(&lA[0][(128 + wv * 8) * 64],  aSrcP[2]);
  GLD(&lA[0][(64 + wv * 8) * 64],   aSrcP[1]);
  GLD(&lA[0][(192 + wv * 8) * 64],  aSrcP[3]);
  VMW(0);
  __builtin_amdgcn_s_barrier();

  for (int t = 0; t < 14; t += 2) {
    KTILE(0, 1, t + 1, 1, VMW(4), VMW(2));
    KTILE(1, 0, t + 2, 1, VMW(4), VMW(2));
  }
  KTILE(0, 1, 15, 1, VMW(4), VMW(2));
  KTILE(1, 0, 0, 0, VMW(0), ((void)0));

  const float be = bias[ei];
#pragma unroll
  for (int i = 0; i < 8; ++i) {
#pragma unroll
    for (int r = 0; r < 4; ++r) {
      const int krow = m0 + wm * 128 + i * 16 + (ln >> 4) * 4 + r;
      const float inv = 1.0f / valbuf[grp * K_SEL + krow];
      unsigned short* trow = tmp + ((size_t)grp * K_SEL + krow) * O_DIM;
#pragma unroll
      for (int j = 0; j < 4; ++j) {
        const int col = n0 + wn * 64 + j * 16 + (ln & 15);
        trow[col] = f2b((acc[i][j][r] + be) * inv);
      }
    }
  }
#undef GLD
#undef VMW
#undef LGKM0
#undef DS_A
#undef DS_B
#undef MFMA16
#undef KTILE
}

// ---------------- per-token gather-reduce: 2 tokens/block, 16B loads ----------------
__global__ __launch_bounds__(256) void reduce_kernel(const unsigned short* __restrict__ tmp,
                                                     const int* __restrict__ cnt,
                                                     const int* __restrict__ hslot,
                                                     float* __restrict__ out) {
  const int t = blockIdx.x * 2 + (threadIdx.x >> 7);   // b*S + s
  const int bi = t >> 11;
  const int l = threadIdx.x & 127;
  const int n = cnt[t];
  float a[8] = {0.f, 0.f, 0.f, 0.f, 0.f, 0.f, 0.f, 0.f};
  for (int h = 0; h < n; ++h) {
    const int u = hslot[t * 16 + h];  // e*K + p
    const u16x8 q = *reinterpret_cast<const u16x8*>(
        tmp + ((size_t)bi * E_NUM * K_SEL + u) * O_DIM + l * 8);
#pragma unroll
    for (int j = 0; j < 8; ++j) a[j] += b2f(q[j]);
  }
  float4 s0 = {a[0], a[1], a[2], a[3]};
  float4 s1 = {a[4], a[5], a[6], a[7]};
  float* op = &out[(size_t)t * O_DIM + l * 8];
  *reinterpret_cast<float4*>(op) = s0;
  *reinterpret_cast<float4*>(op + 4) = s1;
}

extern "C" void kernel_launch(void* const* d_in, const int* in_sizes, int n_in,
                              void* d_out, int out_size, void* d_ws, size_t ws_size,
                              hipStream_t stream) {
  const float* x   = (const float*)d_in[0];
  const float* gw  = (const float*)d_in[1];
  const float* gb  = (const float*)d_in[2];
  const float* w   = (const float*)d_in[3];
  const float* bia = (const float*)d_in[4];
  float* out = (float*)d_out;

  char* ws = (char*)d_ws;
  float*          logits_t = (float*)(ws + 0x0);        // 512 KB
  float*          vals     = (float*)(ws + 0x80000);    // 128 KB
  int*            idxb     = (int*)(ws + 0xA0000);      // 128 KB
  int*            cnt      = (int*)(ws + 0xC0000);      // 32 KB
  int*            hslot    = (int*)(ws + 0xC8000);      // 512 KB
  unsigned short* xbf      = (unsigned short*)(ws + 0x148000);    // 16 MB
  unsigned short* wtb      = (unsigned short*)(ws + 0x1148000);   // 32 MB
  unsigned short* tmp      = (unsigned short*)(ws + 0x3148000);   // 64 MB
  float*          gwt      = (float*)(ws + 0x7148000);            // 64 KB

  gwt_kernel<<<dim3(64 + 8), dim3(256), 0, stream>>>(gw, gwt, cnt);
  prep_kernel<<<dim3(4096 + 2048), dim3(256), 0, stream>>>(w, wtb, x, gwt, gb, logits_t, xbf);
  topk_kernel<<<dim3(B_NUM * E_NUM), dim3(1024), 0, stream>>>(logits_t, vals, idxb, cnt, hslot);
  moe_gemm_kernel<<<dim3(512), dim3(512), 0, stream>>>(xbf, wtb, idxb, vals, bia, tmp);
  reduce_kernel<<<dim3(B_NUM * S_DIM / 2), dim3(256), 0, stream>>>(tmp, cnt, hslot, out);
}